// Round 6
// baseline (1040.457 us; speedup 1.0000x reference)
//
#include <hip/hip_runtime.h>
#include <math.h>
#include <stdint.h>

#define Lr 32
#define Hh 128
#define NCELL (Lr * Lr)
#define NEPS 1e-8f
#define CELLB 33792            // bytes per cell image: 4x8KB pair-chunks + 1KB tail

typedef _Float16 f16;
typedef f16 h2 __attribute__((ext_vector_type(2)));
typedef uint32_t u32;
typedef u32 u32x4 __attribute__((ext_vector_type(4)));
typedef u32 u32x2 __attribute__((ext_vector_type(2)));

// LDS-publish barrier (does NOT touch vmcnt: in-flight weight loads survive).
__device__ __forceinline__ void bar_lds() {
    asm volatile("s_waitcnt lgkmcnt(0)\n\ts_barrier" ::: "memory");
}

template<int CTRL>
__device__ __forceinline__ float dpp_get(float x) {
    return __int_as_float(__builtin_amdgcn_update_dpp(
        0, __float_as_int(x), CTRL, 0xf, 0xf, true));
}
// 0xB1 = quad_perm[1,0,3,2] (xor1), 0x4E = quad_perm[2,3,0,1] (xor2),
// 0x141 = row_half_mirror (xor7), 0x140 = row_mirror (xor15)

__device__ __forceinline__ float rlane(float x, int l) {
    return __int_as_float(__builtin_amdgcn_readlane(__float_as_int(x), l));
}

__device__ __forceinline__ float dot2(h2 a, h2 b, float c) {
    return __builtin_amdgcn_fdot2(a, b, c, false);   // v_dot2_f32_f16
}

__device__ __forceinline__ h2 bch2(u32 v) {
    union { u32 u; h2 h; } cv; cv.u = v; return cv.h;
}
__device__ __forceinline__ float h16(u32 w, int hi) {
    union { unsigned short u; f16 h; } c;
    c.u = (unsigned short)(hi ? (w >> 16) : (w & 0xffff));
    return (float)c.h;
}

__device__ __forceinline__ float fast_tanh(float x) {
    x = fminf(9.f, fmaxf(-9.f, x));
    const float e = __expf(2.f * x);
    return 1.f - 2.f / (e + 1.f);
}

__device__ __forceinline__ int cell_of(int s) {
    const int i = s >> 5, jj = s & 31;
    const int c = (i & 1) ? (Lr - 1 - jj) : jj;
    return i * Lr + c;
}

// W1[cell][k][m] (fp32, k<128, m<130) -> per-cell 33KB image for 512 threads:
//  chunk region (4 x 8KB): [c4<4][t<512] 16B = 4 f16-pairs; thread t
//    (k=t>>2, q=t&3) owns h-pairs p = q*16 + c4*4 + {0..3} = W cols (2+2p,3+2p).
//    -> rnn ISSUE is 4 fully-coalesced dwordx4 per thread.
//  tail region (1KB): [k<128] 8B = f16 {sp0,sp1,sp2,wf}: binary spins fold
//    spin-cols+bias to 3 candidates: sp0=2W[k][1]+2b, sp1=W[k][0]+W[k][1]+2b,
//    sp2=2W[k][0]+2b.
__global__ __launch_bounds__(256)
void transpose_w(const float* __restrict__ W1, const float* __restrict__ b1,
                 const float* __restrict__ Wf, char* __restrict__ Wt) {
    __shared__ float tile[Hh * 130];    // 66.6 KB
    const int cell = blockIdx.x;
    const float* src = W1 + (size_t)cell * (Hh * 130);
    for (int idx = threadIdx.x; idx < Hh * 130; idx += 256)
        tile[idx] = src[idx];
    __syncthreads();
    char* dst = Wt + (size_t)cell * CELLB;
    const int t = threadIdx.x;
    for (int idx = t; idx < 2048; idx += 256) {
        const int c4 = idx >> 9, tt = idx & 511;
        const int kk = tt >> 2, q = tt & 3;
        union { u32x4 v; f16 h[8]; } o;
        for (int j = 0; j < 4; ++j) {
            const int p = q * 16 + c4 * 4 + j;
            o.h[2 * j]     = (f16)tile[kk * 130 + 2 + 2 * p];
            o.h[2 * j + 1] = (f16)tile[kk * 130 + 3 + 2 * p];
        }
        *(u32x4*)(dst + c4 * 8192 + tt * 16) = o.v;
    }
    if (t < Hh) {
        union { u32x2 v; f16 h[4]; } o;
        const float w0 = tile[t * 130 + 0], w1 = tile[t * 130 + 1];
        const float bb = 2.f * b1[cell * Hh + t];
        o.h[0] = (f16)(2.f * w1 + bb);
        o.h[1] = (f16)(w0 + w1 + bb);
        o.h[2] = (f16)(2.f * w0 + bb);
        o.h[3] = (f16)Wf[cell * Hh + t];
        *(u32x2*)(dst + 32768 + t * 8) = o.v;
    }
}

// 512 blocks x 1 batch element, 512 threads (8 waves), 2 blocks/CU
// -> 16 waves/CU = 4 waves/SIMD (round 5 had 2/SIMD at Occupancy 21.6% with
// no pipe >42% busy: latency-bound, thin stall coverage). Lane quad owns
// output k = t>>2; quarter q = t&3 dots 16 of the 64 h-pairs; quad combine
// is 2 in-wave DPP adds. Weights in FOUR rotating register buffers via
// asm-volatile loads (5/cell/thread), counted vmcnt(10) retirement.
__global__ __launch_bounds__(512, 4)
void rnn2d(const float* __restrict__ samples,
           const char* __restrict__ Wt,
           const float* __restrict__ bfv,
           float* __restrict__ out)
{
    __shared__ __align__(16) h2  inp[2][64];        // 64 h-pairs, dbuffered
    __shared__ __align__(16) f16 hvh[Lr * Hh];      // vertical hidden, 8 KB
    __shared__ float smp[NCELL];
    __shared__ float bfs[NCELL];
    __shared__ __align__(16) float fp_[2][8];       // head partials [parity][wave]
    __shared__ int   sidx[2];                       // spin-case 0/1/2 [parity]
    __shared__ float lpb[2];

    const int t = threadIdx.x;
    const int k = t >> 2;                            // output row (0..127)
    const int q = t & 3;                             // m-quarter within quad
    const int w = t >> 6;                            // wave (0..7)
    const int b = blockIdx.x;

    // loop-invariant load offsets (VGPRs)
    u32 vc[4], vt;
    for (int c4 = 0; c4 < 4; ++c4) vc[c4] = (u32)(c4 * 8192 + t * 16);
    vt = (u32)(32768 + k * 8);

    {
        f16* z1 = (f16*)inp;
        for (int idx = t; idx < 2 * 64 * 2; idx += 512) z1[idx] = (f16)0.f;
        f16* z2 = (f16*)hvh;
        for (int idx = t; idx < Lr * Hh; idx += 512) z2[idx] = (f16)0.f;
        for (int idx = t; idx < NCELL; idx += 512) {
            smp[idx] = samples[(size_t)b * NCELL + idx];
            bfs[idx] = bfv[idx];
        }
        if (t == 0) sidx[0] = 0;      // cell 0: xh=xv=0
    }
    float lp = 0.f;

    u32x4 A0,A1,A2,A3, B0,B1,B2,B3, C0,C1,C2,C3, D0,D1,D2,D3;
    u32x2 TA, TB, TC, TD;

// issue the 5 uniform volatile loads for cell S into one register buffer
#define ISSUE(S, W0,W1_,W2_,W3_, TT)                                        \
    {                                                                       \
        const int s_ = ((S) < NCELL) ? (S) : 0;   /* uniform dummy at tail */\
        const char* cb_ = Wt + (size_t)cell_of(s_) * CELLB;                 \
        asm volatile("global_load_dwordx4 %0, %1, %2" : "=v"(W0)  : "v"(vc[0]), "s"(cb_)); \
        asm volatile("global_load_dwordx4 %0, %1, %2" : "=v"(W1_) : "v"(vc[1]), "s"(cb_)); \
        asm volatile("global_load_dwordx4 %0, %1, %2" : "=v"(W2_) : "v"(vc[2]), "s"(cb_)); \
        asm volatile("global_load_dwordx4 %0, %1, %2" : "=v"(W3_) : "v"(vc[3]), "s"(cb_)); \
        asm volatile("global_load_dwordx2 %0, %1, %2" : "=v"(TT)  : "v"(vt),    "s"(cb_)); \
    }

// counted wait: retire everything except the newest 2 stages (2 x 5 ops)
#define WAITP()                                                             \
    asm volatile("s_waitcnt vmcnt(10)" ::: "memory");                       \
    __builtin_amdgcn_sched_barrier(0);

#define DOT4(WQ, QQ, C4)                                                    \
    {                                                                       \
        const u32x4 v_ = (WQ);                                              \
        const uint4 xa_ = *(const uint4*)&inp[QQ][q * 16 + (C4) * 4];       \
        a00 = dot2(bch2(v_.x), bch2(xa_.x), a00);                           \
        a01 = dot2(bch2(v_.y), bch2(xa_.y), a01);                           \
        a02 = dot2(bch2(v_.z), bch2(xa_.z), a02);                           \
        a03 = dot2(bch2(v_.w), bch2(xa_.w), a03);                           \
    }

#define PROC(S, Q, W0,W1_,W2_,W3_, TT)                                      \
    {                                                                       \
        const int i_ = (S) >> 5, j_ = (S) & 31;                             \
        const int c_ = (i_ & 1) ? (Lr - 1 - j_) : j_;                       \
        const int sn_ = ((S) + 1 < NCELL) ? (S) + 1 : (S);                  \
        const int in_ = sn_ >> 5, jn_ = sn_ & 31;                           \
        const int cn_ = (in_ & 1) ? (Lr - 1 - jn_) : jn_;                   \
        const float hvn = (float)hvh[cn_ * Hh + k];                         \
        /* deferred lp tail for cell S-1: lane 4 of waves 4/5 (off the */   \
        /* critical waves 0/1 which host t==0 bookkeeping) */               \
        if (((t & 63) == 4) && (w == 4 || w == 5) && (S) > 0) {             \
            const int cp_ = cell_of((S) - 1);                               \
            const float4 fa_ = *(const float4*)&fp_[Q][0];                  \
            const float4 fb_ = *(const float4*)&fp_[Q][4];                  \
            const float z_ = ((fa_.x + fa_.y) + (fa_.z + fa_.w))            \
                           + ((fb_.x + fb_.y) + (fb_.z + fb_.w)) + bfs[cp_];\
            const float xh_ = 1.f / (1.f + __expf(-z_));                    \
            const float m_ = smp[cp_];                                      \
            lp += (w == 4) ? __logf(xh_ + NEPS) * m_                        \
                           : __logf(1.f - xh_ + NEPS) * (1.f - m_);         \
        }                                                                   \
        /* 16-pair quarter-dot: register weights x broadcast LDS input */   \
        float a00 = 0.f, a01 = 0.f, a02 = 0.f, a03 = 0.f;                   \
        DOT4(W0,  Q, 0) DOT4(W1_, Q, 1)                                     \
        DOT4(W2_, Q, 2) DOT4(W3_, Q, 3)                                     \
        float s0 = (a00 + a01) + (a02 + a03);                               \
        s0 += dpp_get<0xB1>(s0);   /* quad combine: xor1 */                 \
        s0 += dpp_get<0x4E>(s0);   /* xor2 -> full 64-pair dot, all lanes */\
        /* spin-case + folded bias, added post-reduce (once) */             \
        const int sx = sidx[Q];                                             \
        const float t0_ = h16(TT.x, 0), t1_ = h16(TT.x, 1);                 \
        const float t2_ = h16(TT.y, 0), wfv = h16(TT.y, 1);                 \
        s0 += (sx == 2) ? t2_ : ((sx == 1) ? t1_ : t0_);                    \
        const float h0 = fast_tanh(s0);                                     \
        /* head: per-wave sum of h[k]*wf[k] (quad-duplicated, so xor7 */    \
        /* combines adjacent k, xor15 the 8-groups, readlane the rows) */   \
        float f0 = h0 * wfv;                                                \
        f0 += dpp_get<0x141>(f0);                                           \
        f0 += dpp_get<0x140>(f0);                                           \
        f0 = f0 + rlane(f0, 16) + rlane(f0, 32) + rlane(f0, 48);            \
        if ((S) + 1 < NCELL) {                                              \
            const float v0 = ((jn_ == 0) ? 0.f : h0)                        \
                           + ((cn_ == c_) ? h0 : hvn);                      \
            const float v0p = __shfl_down(v0, 4);  /* partner k's value */  \
            if ((t & 7) == 0) {                                             \
                h2 u0; u0.x = (f16)v0; u0.y = (f16)v0p;                     \
                inp[(Q) ^ 1][t >> 3] = u0;                                  \
            }                                                               \
            if (t == 0) {                                                   \
                const float xh0 = (jn_ == 0) ? 0.f : smp[i_ * Lr + c_];     \
                const float xv0 = (in_ == 0) ? 0.f                          \
                                             : smp[(in_ - 1) * Lr + cn_];   \
                sidx[(Q) ^ 1] = (int)(xh0 + xv0);                           \
            }                                                               \
        }                                                                   \
        if ((t & 3) == 0) hvh[c_ * Hh + k] = (f16)h0;  /* k-partitioned */  \
        if ((t & 63) == 0) fp_[(Q) ^ 1][w] = f0;                            \
        bar_lds();   /* single LDS barrier per cell; vmcnt untouched */     \
    }

    // prologue: buffers for cells 0 and 1 in flight; first in-loop WAITP
    // (vmcnt 10 = B's 5 + C's 5) guarantees buffer A (cell 0) has landed.
    ISSUE(0, A0,A1,A2,A3, TA);
    ISSUE(1, B0,B1,B2,B3, TB);
    __syncthreads();

    for (int s = 0; s < NCELL; s += 4) {
        ISSUE(s + 2, C0,C1,C2,C3, TC); WAITP();
        PROC(s,     0, A0,A1,A2,A3, TA);
        ISSUE(s + 3, D0,D1,D2,D3, TD); WAITP();
        PROC(s + 1, 1, B0,B1,B2,B3, TB);
        ISSUE(s + 4, A0,A1,A2,A3, TA); WAITP();
        PROC(s + 2, 0, C0,C1,C2,C3, TC);
        ISSUE(s + 5, B0,B1,B2,B3, TB); WAITP();
        PROC(s + 3, 1, D0,D1,D2,D3, TD);
    }
#undef ISSUE
#undef WAITP
#undef DOT4
#undef PROC

    // tail: lp for cell 1023 (fp_ parity 0, published by the final barrier)
    if (((t & 63) == 4) && (w == 4 || w == 5)) {
        const int cp_ = cell_of(NCELL - 1);
        const float4 fa_ = *(const float4*)&fp_[0][0];
        const float4 fb_ = *(const float4*)&fp_[0][4];
        const float z_ = ((fa_.x + fa_.y) + (fa_.z + fa_.w))
                       + ((fb_.x + fb_.y) + (fb_.z + fb_.w)) + bfs[cp_];
        const float xh_ = 1.f / (1.f + __expf(-z_));
        const float m_ = smp[cp_];
        lp += (w == 4) ? __logf(xh_ + NEPS) * m_
                       : __logf(1.f - xh_ + NEPS) * (1.f - m_);
        lpb[w - 4] = lp;
    }
    __syncthreads();
    if (t == 0) out[b] = lpb[0] + lpb[1];
}

extern "C" void kernel_launch(void* const* d_in, const int* in_sizes, int n_in,
                              void* d_out, int out_size, void* d_ws, size_t ws_size,
                              hipStream_t stream) {
    const float* samples = (const float*)d_in[0];
    const float* W1      = (const float*)d_in[1];
    const float* b1      = (const float*)d_in[2];
    const float* Wf      = (const float*)d_in[3];
    const float* bf      = (const float*)d_in[4];
    float* outp = (float*)d_out;
    char* Wt = (char*)d_ws;   // 1024 * 33792 B = 34.6 MB

    transpose_w<<<1024, 256, 0, stream>>>(W1, b1, Wf, Wt);
    rnn2d<<<512, 512, 0, stream>>>(samples, Wt, bf, outp);
}